// Round 4
// baseline (310.197 us; speedup 1.0000x reference)
//
#include <hip/hip_runtime.h>
#include <hip/hip_bf16.h>
#include <stdint.h>

#define B_ 32
#define N_ 1024
#define H_ 256
#define PF_PITCH 520   // shorts per ks row (1040 B -> +4 banks per ks, 16B-aligned)
#define GEMM_BLOCKS (B_ * 16)   // 512

typedef short bf16x8 __attribute__((ext_vector_type(8)));
typedef float floatx4 __attribute__((ext_vector_type(4)));

__device__ inline unsigned short f2bs(float x) {
    __hip_bfloat16 h = __float2bfloat16(x);
    return __builtin_bit_cast(unsigned short, h);
}

// ---------------------------------------------------------------------------
// Launch 1: k_pre = {prep (blocks 0..31)} U {uvec (blocks 32..287)}.
// prep: W -> fragment-ordered bf16 WtF. uvec: u = {Wi,Wc}^T @ {a1,a2}.
// ---------------------------------------------------------------------------
__global__ __launch_bounds__(256)
void k_pre(const float* __restrict__ Wi, const float* __restrict__ Wc,
           const float* __restrict__ a, float* __restrict__ U,
           unsigned short* __restrict__ WtFi, unsigned short* __restrict__ WtFc) {
    int bid = blockIdx.x;
    int t = threadIdx.x;
    if (bid < 32) {
        // ---- prep ----
        __shared__ float tile[64][65];   // [k_local][n_local]
        int mat = bid >> 4;
        int tr = ((bid >> 2) & 3) * 64;  // k-tile origin
        int tc = (bid & 3) * 64;         // n-tile origin
        const float* W = mat ? Wc : Wi;
        unsigned short* WtF = mat ? WtFc : WtFi;
        int rr = t >> 2, c4 = (t & 3) * 16;
        const float* src = W + (size_t)(tr + rr) * H_ + tc + c4;
#pragma unroll
        for (int j = 0; j < 4; ++j) {
            float4 v = *reinterpret_cast<const float4*>(src + j * 4);
            tile[rr][c4 + 4 * j + 0] = v.x;
            tile[rr][c4 + 4 * j + 1] = v.y;
            tile[rr][c4 + 4 * j + 2] = v.z;
            tile[rr][c4 + 4 * j + 3] = v.w;
        }
        __syncthreads();
#pragma unroll
        for (int h = 0; h < 2; ++h) {
            int s = h * 256 + t;
            int ksl = s >> 8;
            int cl  = (s >> 6) & 3;
            int ll  = s & 63;
            int m16v = ll & 15, quadv = ll >> 4;
            int nloc = cl * 16 + m16v;
            int kb = ksl * 32 + quadv * 8;
            unsigned int pk[4];
#pragma unroll
            for (int jj = 0; jj < 4; ++jj) {
                unsigned short lo = f2bs(tile[kb + 2 * jj][nloc]);
                unsigned short hi = f2bs(tile[kb + 2 * jj + 1][nloc]);
                pk[jj] = (unsigned int)lo | ((unsigned int)hi << 16);
            }
            int ksg = (tr >> 5) + ksl;
            int cg  = (tc >> 4) + cl;
            *reinterpret_cast<uint4*>(WtF + ((size_t)(ksg * 16 + cg) * 64 + ll) * 8) =
                *reinterpret_cast<uint4*>(pk);
        }
    } else {
        // ---- uvec ----
        int k = bid - 32;
        float wi = Wi[k * H_ + t];
        float wc = Wc[k * H_ + t];
        float a1 = a[t], a2 = a[H_ + t];
        float p0 = wi * a1, p1 = wc * a1, p2 = wi * a2, p3 = wc * a2;
        for (int off = 32; off; off >>= 1) {
            p0 += __shfl_xor(p0, off);
            p1 += __shfl_xor(p1, off);
            p2 += __shfl_xor(p2, off);
            p3 += __shfl_xor(p3, off);
        }
        __shared__ float red[4][4];
        int w = t >> 6;
        if ((t & 63) == 0) { red[w][0] = p0; red[w][1] = p1; red[w][2] = p2; red[w][3] = p3; }
        __syncthreads();
        if (t == 0) {
            U[0 * H_ + k] = red[0][0] + red[1][0] + red[2][0] + red[3][0];
            U[1 * H_ + k] = red[0][1] + red[1][1] + red[2][1] + red[3][1];
            U[2 * H_ + k] = red[0][2] + red[1][2] + red[2][2] + red[3][2];
            U[3 * H_ + k] = red[0][3] + red[1][3] + red[2][3] + red[3][3];
        }
    }
}

// ---------------------------------------------------------------------------
// Launch 2: k_main = {gemm (blocks 0..511, full 256-col tiles)} U
// {abits (blocks 512.., A -> bitmask)}. The abits stream (134 MB, BW-bound)
// co-schedules with gemm's compute-bound blocks: total ~= max, not sum.
// gemm: one block = 64 rows x 256 cols, acc[16], 16 KB/ks LDS staging,
// score-dots in a pre-loop (register pressure capped for (256,2)).
// ---------------------------------------------------------------------------
__global__ __launch_bounds__(256, 2)
void k_main(const float* __restrict__ inp, const int* __restrict__ l,
            const unsigned short* __restrict__ WtFi, const unsigned short* __restrict__ WtFc,
            unsigned short* __restrict__ WhF, const float* __restrict__ U,
            float* __restrict__ Wh1, float* __restrict__ Wh2,
            const float* __restrict__ A, unsigned int* __restrict__ M) {
    int bid = blockIdx.x;
    int t = threadIdx.x;
    int w = t >> 6;
    int lane = t & 63;
    if (bid >= GEMM_BLOCKS) {
        // ---- abits: one row of A -> 128 B bitmask ----
        size_t row = bid - GEMM_BLOCKS;                 // b*N + i
        const float* Ar = A + row * N_ + w * 256 + lane * 4;
        float4 v = *reinterpret_cast<const float4*>(Ar);
        unsigned long long b0 = __ballot(v.x > 0.f);
        unsigned long long b1 = __ballot(v.y > 0.f);
        unsigned long long b2 = __ballot(v.z > 0.f);
        unsigned long long b3 = __ballot(v.w > 0.f);
        if (lane == 0) {
            unsigned int* Mp = M + (row * 4 + w) * 8;
            uint4 v0 = {(unsigned int)b0, (unsigned int)(b0 >> 32),
                        (unsigned int)b1, (unsigned int)(b1 >> 32)};
            uint4 v1 = {(unsigned int)b2, (unsigned int)(b2 >> 32),
                        (unsigned int)b3, (unsigned int)(b3 >> 32)};
            *reinterpret_cast<uint4*>(Mp) = v0;
            *reinterpret_cast<uint4*>(Mp + 4) = v1;
        }
        return;
    }

    // ---- gemm ----
    __shared__ unsigned short bbuf[2][8192];  // 16 KB per buffer
    int blk = bid;
    int b  = blk >> 4;
    int r0 = (blk & 15) * 64;
    int quad = lane >> 4, m16 = lane & 15;
    int rowb = r0 + w * 16;

    int l0 = l[2 * b], l1 = l[2 * b + 1];
    bool allI = (l0 <= r0) && (r0 + 64 <= l1);
    bool allC = (l1 <= r0) || (l0 >= r0 + 64);
    int npass = (allI || allC) ? 1 : 2;

    int row = rowb + m16;
    bool sel = (row >= l0) && (row < l1);
    const float* xrow = inp + ((size_t)(b * N_ + row)) * H_;
    const float* u1 = U + (sel ? 0 : H_);
    const float* u2 = U + 2 * H_ + (sel ? 0 : H_);

    // score-dot pre-loop (independent of W-pass; xrow re-read later from cache)
    float d1 = 0.f, d2 = 0.f;
#pragma unroll 2
    for (int ks = 0; ks < 8; ++ks) {
        const float4 xa = *reinterpret_cast<const float4*>(xrow + ks * 32 + quad * 8);
        const float4 xb = *reinterpret_cast<const float4*>(xrow + ks * 32 + quad * 8 + 4);
        const float4 ua = *reinterpret_cast<const float4*>(u1 + ks * 32 + quad * 8);
        const float4 ub = *reinterpret_cast<const float4*>(u1 + ks * 32 + quad * 8 + 4);
        const float4 va = *reinterpret_cast<const float4*>(u2 + ks * 32 + quad * 8);
        const float4 vb = *reinterpret_cast<const float4*>(u2 + ks * 32 + quad * 8 + 4);
        d1 += xa.x * ua.x + xa.y * ua.y + xa.z * ua.z + xa.w * ua.w
            + xb.x * ub.x + xb.y * ub.y + xb.z * ub.z + xb.w * ub.w;
        d2 += xa.x * va.x + xa.y * va.y + xa.z * va.z + xa.w * va.w
            + xb.x * vb.x + xb.y * vb.y + xb.z * vb.z + xb.w * vb.w;
    }
    d1 += __shfl_xor(d1, 16); d1 += __shfl_xor(d1, 32);
    d2 += __shfl_xor(d2, 16); d2 += __shfl_xor(d2, 32);
    if (quad == 0) {
        Wh1[b * N_ + rowb + m16] = d1;
        Wh2[b * N_ + rowb + m16] = d2;
    }

    unsigned short* fb = WhF + (size_t)b * (N_ * H_);
    int j0 = rowb + quad * 4;
    int ksO = j0 >> 5;
    int laneF = m16 + 16 * ((j0 & 31) >> 3);
    int jj0 = j0 & 7;

    for (int pass = 0; pass < npass; ++pass) {
        const unsigned short* gbase =
            (npass == 1) ? (allI ? WtFi : WtFc) : (pass == 0 ? WtFi : WtFc);

        floatx4 acc[16];
#pragma unroll
        for (int c = 0; c < 16; ++c) acc[c] = (floatx4){0.f, 0.f, 0.f, 0.f};

        {   // prologue: stage ks=0 into buf0 (linear 16 KB copy, 64 B/thread)
            const unsigned short* s0 = gbase + (size_t)t * 32;
#pragma unroll
            for (int j = 0; j < 4; ++j)
                *reinterpret_cast<uint4*>(&bbuf[0][t * 32 + j * 8]) =
                    *reinterpret_cast<const uint4*>(s0 + j * 8);
        }
        for (int ks = 0; ks < 8; ++ks) {
            __syncthreads();
            uint4 v[4];
            if (ks < 7) {
                const unsigned short* sn = gbase + (size_t)(ks + 1) * 8192 + t * 32;
#pragma unroll
                for (int j = 0; j < 4; ++j)
                    v[j] = *reinterpret_cast<const uint4*>(sn + j * 8);
            }
            const float4 xa = *reinterpret_cast<const float4*>(xrow + ks * 32 + quad * 8);
            const float4 xb = *reinterpret_cast<const float4*>(xrow + ks * 32 + quad * 8 + 4);
            unsigned int pk0 = (unsigned int)f2bs(xa.x) | ((unsigned int)f2bs(xa.y) << 16);
            unsigned int pk1 = (unsigned int)f2bs(xa.z) | ((unsigned int)f2bs(xa.w) << 16);
            unsigned int pk2 = (unsigned int)f2bs(xb.x) | ((unsigned int)f2bs(xb.y) << 16);
            unsigned int pk3 = (unsigned int)f2bs(xb.z) | ((unsigned int)f2bs(xb.w) << 16);
            uint4 apk = {pk0, pk1, pk2, pk3};
            bf16x8 af = __builtin_bit_cast(bf16x8, apk);

            const unsigned short* bptr = &bbuf[ks & 1][lane * 8];
#pragma unroll
            for (int c = 0; c < 16; ++c) {
                bf16x8 bfr = *reinterpret_cast<const bf16x8*>(bptr + c * 512);
                acc[c] = __builtin_amdgcn_mfma_f32_16x16x32_bf16(af, bfr, acc[c], 0, 0, 0);
            }
            if (ks < 7) {
#pragma unroll
                for (int j = 0; j < 4; ++j)
                    *reinterpret_cast<uint4*>(&bbuf[(ks + 1) & 1][t * 32 + j * 8]) = v[j];
            }
        }
        __syncthreads();

#pragma unroll
        for (int c = 0; c < 16; ++c) {
            size_t base = ((size_t)((ksO * 16 + c) * 64) + laneF) * 8 + jj0;
            if (npass == 1) {
                unsigned int lo = (unsigned int)f2bs(acc[c][0]) | ((unsigned int)f2bs(acc[c][1]) << 16);
                unsigned int hi = (unsigned int)f2bs(acc[c][2]) | ((unsigned int)f2bs(acc[c][3]) << 16);
                uint2 v2 = {lo, hi};
                *reinterpret_cast<uint2*>(fb + base) = v2;
            } else {
                bool want[4]; bool all = true, none = true;
#pragma unroll
                for (int r = 0; r < 4; ++r) {
                    int j = j0 + r;
                    bool s2 = (j >= l0) && (j < l1);
                    want[r] = (pass == 0) ? s2 : !s2;
                    all = all && want[r]; none = none && !want[r];
                }
                if (all) {
                    unsigned int lo = (unsigned int)f2bs(acc[c][0]) | ((unsigned int)f2bs(acc[c][1]) << 16);
                    unsigned int hi = (unsigned int)f2bs(acc[c][2]) | ((unsigned int)f2bs(acc[c][3]) << 16);
                    uint2 v2 = {lo, hi};
                    *reinterpret_cast<uint2*>(fb + base) = v2;
                } else if (!none) {
#pragma unroll
                    for (int r = 0; r < 4; ++r)
                        if (want[r]) fb[base + r] = f2bs(acc[c][r]);
                }
            }
        }
    }
}

// ---------------------------------------------------------------------------
// Launch 3: k_attn = fused masked-softmax + P@Wh (MFMA) + elu. R3 mask-based
// phase 1 + two changes: (1) row denominators via fp32 64-lane shuffle
// reduce in phase 1 (removes the 64 ones-MFMAs per block = 20% of MFMA
// work, and is more accurate); (2) phase-2 ks-loop uses explicit 1-step
// register prefetch of af/bfv to deepen load pipelining over L2-resident
// WhF. Grid = B*(N/32) = 1024, XCD-swizzled, 2 blocks/CU.
// ---------------------------------------------------------------------------
__global__ __launch_bounds__(256)
void k_attn(const unsigned int* __restrict__ Mask, const float* __restrict__ Wh1,
            const float* __restrict__ Wh2, const unsigned short* __restrict__ WhF,
            float* __restrict__ out) {
    __shared__ unsigned short pfrag[2][32 * PF_PITCH];  // 2 x 33,280 B
    __shared__ float rsum[2][16];
    int t = threadIdx.x, w = t >> 6, lane = t & 63;
    int bi = blockIdx.x;
    int b = (bi & 7) * 4 + (bi >> 8);   // XCD-swizzle
    int tile = (bi >> 3) & 31;
    int rowbase = tile * 32;

    const float* Wh2b = Wh2 + b * N_;
    float4 w2v[4];
#pragma unroll
    for (int ch = 0; ch < 4; ++ch)
        w2v[ch] = *reinterpret_cast<const float4*>(Wh2b + ch * 256 + lane * 4);

    int ksl = lane >> 3;
    int q2 = (lane >> 1) & 3;
    int jj0 = (lane & 1) * 4;
    int d  = lane >> 5;    // mask dword select
    int lb = lane & 31;    // mask bit select

#pragma unroll
    for (int tt = 0; tt < 2; ++tt) {
#pragma unroll
        for (int q = 0; q < 4; ++q) {
            int m = w * 4 + q;                 // row within 16-tile
            int i = rowbase + tt * 16 + m;
            float wh1 = Wh1[b * N_ + i];
            // wave-uniform mask row: 32 dwords = 16 x uint2
            const uint2* Mrow = reinterpret_cast<const uint2*>(
                Mask + ((size_t)(b * N_ + i)) * 32);
            unsigned int wv[4][4];
#pragma unroll
            for (int ch = 0; ch < 4; ++ch)
#pragma unroll
                for (int c = 0; c < 4; ++c) {
                    uint2 u = Mrow[ch * 4 + c];
                    wv[ch][c] = d ? u.y : u.x;
                }
            // swizzled slot address (matches phase-2 read swizzle)
            int s = m + 16 * q2;
            int sw = s ^ ((s >> 3) & 7);
            int sls = sw * 8 + jj0;
            float rp = 0.f;
#pragma unroll
            for (int ch = 0; ch < 4; ++ch) {
                float aa[4];
#pragma unroll
                for (int c = 0; c < 4; ++c)
                    aa[c] = (float)((wv[ch][c] >> lb) & 1u);
                if ((i >> 2) == (ch * 64 + lane)) aa[i & 3] += 1.0f;  // A + I
                float ww[4] = {w2v[ch].x, w2v[ch].y, w2v[ch].z, w2v[ch].w};
                float p[4];
#pragma unroll
                for (int c = 0; c < 4; ++c) {
                    float e  = (wh1 + ww[c]) * aa[c];
                    float lv = fmaxf(e, 0.2f * e);          // leaky_relu
                    p[c] = aa[c] > 0.f ? __expf(lv) : 0.f;  // no max-subtraction
                }
                rp += (p[0] + p[1]) + (p[2] + p[3]);
                unsigned int lo = (unsigned int)f2bs(p[0]) | ((unsigned int)f2bs(p[1]) << 16);
                unsigned int hi = (unsigned int)f2bs(p[2]) | ((unsigned int)f2bs(p[3]) << 16);
                uint2 v = {lo, hi};
                int ks = ch * 8 + ksl;
                *reinterpret_cast<uint2*>(pfrag[tt] + ks * PF_PITCH + sls) = v;
            }
            // fp32 softmax denominator: full 64-lane reduce
            for (int off = 32; off; off >>= 1) rp += __shfl_xor(rp, off);
            if (lane == 0) rsum[tt][m] = rp;
        }
    }
    __syncthreads();

    // Phase 2: P[32 x 1024] @ Wh[1024 x 256] with 1-step register prefetch.
    const unsigned short* WB = WhF + (size_t)b * (N_ * H_);
    int rs = (lane ^ ((lane >> 3) & 7)) * 8;   // swizzled read offset (shorts)
    floatx4 acc0[4], acc1[4];
#pragma unroll
    for (int cc = 0; cc < 4; ++cc) {
        acc0[cc] = (floatx4){0.f, 0.f, 0.f, 0.f};
        acc1[cc] = (floatx4){0.f, 0.f, 0.f, 0.f};
    }
    bf16x8 af0 = *reinterpret_cast<const bf16x8*>(pfrag[0] + rs);
    bf16x8 af1 = *reinterpret_cast<const bf16x8*>(pfrag[1] + rs);
    bf16x8 bfv[4];
#pragma unroll
    for (int cc = 0; cc < 4; ++cc)
        bfv[cc] = *reinterpret_cast<const bf16x8*>(
            WB + ((size_t)((w * 4 + cc) * 64 + lane)) * 8);
    for (int ks = 0; ks < 32; ++ks) {
        bf16x8 naf0, naf1, nbf[4];
        if (ks < 31) {
            naf0 = *reinterpret_cast<const bf16x8*>(pfrag[0] + (ks + 1) * PF_PITCH + rs);
            naf1 = *reinterpret_cast<const bf16x8*>(pfrag[1] + (ks + 1) * PF_PITCH + rs);
#pragma unroll
            for (int cc = 0; cc < 4; ++cc)
                nbf[cc] = *reinterpret_cast<const bf16x8*>(
                    WB + ((size_t)(((ks + 1) * 16 + w * 4 + cc) * 64 + lane)) * 8);
        }
#pragma unroll
        for (int cc = 0; cc < 4; ++cc) {
            acc0[cc] = __builtin_amdgcn_mfma_f32_16x16x32_bf16(af0, bfv[cc], acc0[cc], 0, 0, 0);
            acc1[cc] = __builtin_amdgcn_mfma_f32_16x16x32_bf16(af1, bfv[cc], acc1[cc], 0, 0, 0);
        }
        if (ks < 31) {
            af0 = naf0; af1 = naf1;
#pragma unroll
            for (int cc = 0; cc < 4; ++cc) bfv[cc] = nbf[cc];
        }
    }

    // Epilogue: normalize (fp32 sums from LDS), elu, store.
    int quad = lane >> 4, m16 = lane & 15;
    float inv0[4], inv1[4];
#pragma unroll
    for (int r = 0; r < 4; ++r) {
        inv0[r] = 1.0f / rsum[0][quad * 4 + r];
        inv1[r] = 1.0f / rsum[1][quad * 4 + r];
    }
#pragma unroll
    for (int cc = 0; cc < 4; ++cc) {
        int col = (w * 4 + cc) * 16 + m16;
#pragma unroll
        for (int r = 0; r < 4; ++r) {
            int m = quad * 4 + r;
            float v0 = acc0[cc][r] * inv0[r];
            v0 = v0 > 0.f ? v0 : __expf(v0) - 1.0f;
            out[((size_t)(b * N_ + rowbase + m)) * H_ + col] = v0;
            float v1 = acc1[cc][r] * inv1[r];
            v1 = v1 > 0.f ? v1 : __expf(v1) - 1.0f;
            out[((size_t)(b * N_ + rowbase + 16 + m)) * H_ + col] = v1;
        }
    }
}

// ---------------------------------------------------------------------------
extern "C" void kernel_launch(void* const* d_in, const int* in_sizes, int n_in,
                              void* d_out, int out_size, void* d_ws, size_t ws_size,
                              hipStream_t stream) {
    const float* inp = (const float*)d_in[0];
    const float* A   = (const float*)d_in[1];
    const int*   l   = (const int*)d_in[2];
    const float* Wi  = (const float*)d_in[3];
    const float* Wc  = (const float*)d_in[4];
    const float* a   = (const float*)d_in[5];
    float* out = (float*)d_out;

    char* ws = (char*)d_ws;
    size_t off = 0;
    unsigned short* WhF  = (unsigned short*)(ws + off); off += (size_t)B_ * N_ * H_ * 2;
    float* Wh1 = (float*)(ws + off); off += (size_t)B_ * N_ * 4;
    float* Wh2 = (float*)(ws + off); off += (size_t)B_ * N_ * 4;
    float* U   = (float*)(ws + off); off += 4 * H_ * 4;
    unsigned short* WtFi = (unsigned short*)(ws + off); off += (size_t)H_ * H_ * 2;
    unsigned short* WtFc = (unsigned short*)(ws + off); off += (size_t)H_ * H_ * 2;
    unsigned int* Mask = (unsigned int*)(ws + off); off += (size_t)B_ * N_ * 32 * 4;

    k_pre<<<32 + H_, 256, 0, stream>>>(Wi, Wc, a, U, WtFi, WtFc);
    k_main<<<GEMM_BLOCKS + B_ * N_, 256, 0, stream>>>(inp, l, WtFi, WtFc, WhF, U,
                                                      Wh1, Wh2, A, Mask);
    k_attn<<<B_ * (N_ / 32), 256, 0, stream>>>(Mask, Wh1, Wh2, WhF, out);
}

// Round 5
// 299.837 us; speedup vs baseline: 1.0345x; 1.0345x over previous
//
#include <hip/hip_runtime.h>
#include <hip/hip_bf16.h>
#include <stdint.h>

#define B_ 32
#define N_ 1024
#define H_ 256
#define PF_PITCH 520   // shorts per ks row (1040 B -> +4 banks per ks, 16B-aligned)

typedef short bf16x8 __attribute__((ext_vector_type(8)));
typedef float floatx4 __attribute__((ext_vector_type(4)));

__device__ inline unsigned short f2bs(float x) {
    __hip_bfloat16 h = __float2bfloat16(x);
    return __builtin_bit_cast(unsigned short, h);
}

// ---------------------------------------------------------------------------
// k_pre = {prep (blocks 0..31)} U {uvec (blocks 32..287)}.
// prep: W -> fragment-ordered bf16 WtF. uvec: u = {Wi,Wc}^T @ {a1,a2}.
// ---------------------------------------------------------------------------
__global__ __launch_bounds__(256)
void k_pre(const float* __restrict__ Wi, const float* __restrict__ Wc,
           const float* __restrict__ a, float* __restrict__ U,
           unsigned short* __restrict__ WtFi, unsigned short* __restrict__ WtFc) {
    int bid = blockIdx.x;
    int t = threadIdx.x;
    if (bid < 32) {
        // ---- prep ----
        __shared__ float tile[64][65];   // [k_local][n_local]
        int mat = bid >> 4;
        int tr = ((bid >> 2) & 3) * 64;  // k-tile origin
        int tc = (bid & 3) * 64;         // n-tile origin
        const float* W = mat ? Wc : Wi;
        unsigned short* WtF = mat ? WtFc : WtFi;
        int rr = t >> 2, c4 = (t & 3) * 16;
        const float* src = W + (size_t)(tr + rr) * H_ + tc + c4;
#pragma unroll
        for (int j = 0; j < 4; ++j) {
            float4 v = *reinterpret_cast<const float4*>(src + j * 4);
            tile[rr][c4 + 4 * j + 0] = v.x;
            tile[rr][c4 + 4 * j + 1] = v.y;
            tile[rr][c4 + 4 * j + 2] = v.z;
            tile[rr][c4 + 4 * j + 3] = v.w;
        }
        __syncthreads();
#pragma unroll
        for (int h = 0; h < 2; ++h) {
            int s = h * 256 + t;
            int ksl = s >> 8;
            int cl  = (s >> 6) & 3;
            int ll  = s & 63;
            int m16v = ll & 15, quadv = ll >> 4;
            int nloc = cl * 16 + m16v;
            int kb = ksl * 32 + quadv * 8;
            unsigned int pk[4];
#pragma unroll
            for (int jj = 0; jj < 4; ++jj) {
                unsigned short lo = f2bs(tile[kb + 2 * jj][nloc]);
                unsigned short hi = f2bs(tile[kb + 2 * jj + 1][nloc]);
                pk[jj] = (unsigned int)lo | ((unsigned int)hi << 16);
            }
            int ksg = (tr >> 5) + ksl;
            int cg  = (tc >> 4) + cl;
            *reinterpret_cast<uint4*>(WtF + ((size_t)(ksg * 16 + cg) * 64 + ll) * 8) =
                *reinterpret_cast<uint4*>(pk);
        }
    } else {
        // ---- uvec ----
        int k = bid - 32;
        float wi = Wi[k * H_ + t];
        float wc = Wc[k * H_ + t];
        float a1 = a[t], a2 = a[H_ + t];
        float p0 = wi * a1, p1 = wc * a1, p2 = wi * a2, p3 = wc * a2;
        for (int off = 32; off; off >>= 1) {
            p0 += __shfl_xor(p0, off);
            p1 += __shfl_xor(p1, off);
            p2 += __shfl_xor(p2, off);
            p3 += __shfl_xor(p3, off);
        }
        __shared__ float red[4][4];
        int w = t >> 6;
        if ((t & 63) == 0) { red[w][0] = p0; red[w][1] = p1; red[w][2] = p2; red[w][3] = p3; }
        __syncthreads();
        if (t == 0) {
            U[0 * H_ + k] = red[0][0] + red[1][0] + red[2][0] + red[3][0];
            U[1 * H_ + k] = red[0][1] + red[1][1] + red[2][1] + red[3][1];
            U[2 * H_ + k] = red[0][2] + red[1][2] + red[2][2] + red[3][2];
            U[3 * H_ + k] = red[0][3] + red[1][3] + red[2][3] + red[3][3];
        }
    }
}

// ---------------------------------------------------------------------------
// k_abits: A (binary fp32, 134 MB) -> bitmask M (4 MB). SEPARATE kernel
// (no LDS inherited -> full occupancy), 16 rows per block, 4-row unrolled
// batches: 4 independent 16 B loads in flight per thread before any
// ballot consumes them. 2048 blocks.
// ---------------------------------------------------------------------------
__global__ __launch_bounds__(256)
void k_abits(const float* __restrict__ A, unsigned int* __restrict__ M) {
    int t = threadIdx.x, w = t >> 6, lane = t & 63;
    int base = blockIdx.x * 16;
#pragma unroll
    for (int i0 = 0; i0 < 16; i0 += 4) {
        float4 v[4];
#pragma unroll
        for (int k = 0; k < 4; ++k) {
            size_t row = (size_t)(base + i0 + k);
            v[k] = *reinterpret_cast<const float4*>(A + row * N_ + w * 256 + lane * 4);
        }
#pragma unroll
        for (int k = 0; k < 4; ++k) {
            size_t row = (size_t)(base + i0 + k);
            unsigned long long b0 = __ballot(v[k].x > 0.f);
            unsigned long long b1 = __ballot(v[k].y > 0.f);
            unsigned long long b2 = __ballot(v[k].z > 0.f);
            unsigned long long b3 = __ballot(v[k].w > 0.f);
            if (lane == 0) {
                unsigned int* Mp = M + (row * 4 + w) * 8;
                uint4 v0 = {(unsigned int)b0, (unsigned int)(b0 >> 32),
                            (unsigned int)b1, (unsigned int)(b1 >> 32)};
                uint4 v1 = {(unsigned int)b2, (unsigned int)(b2 >> 32),
                            (unsigned int)b3, (unsigned int)(b3 >> 32)};
                *reinterpret_cast<uint4*>(Mp) = v0;
                *reinterpret_cast<uint4*>(Mp + 4) = v1;
            }
        }
    }
}

// ---------------------------------------------------------------------------
// k_gemm: Wh = inp @ W_sel(row) via MFMA, full 256-col tiles (one block =
// 64 rows x 256 cols, acc[16]): halves inp traffic and score-dot work vs
// the 2x128-col split. Staging fixed to conflict-free 16 B/thread x 4
// contiguous chunks (R4's 64 B/thread pattern was a 32-way bank conflict,
// 1.77M SQ_LDS_BANK_CONFLICT). Score-dots in a pre-loop. Grid 512.
// ---------------------------------------------------------------------------
__global__ __launch_bounds__(256, 2)
void k_gemm(const float* __restrict__ inp, const int* __restrict__ l,
            const unsigned short* __restrict__ WtFi, const unsigned short* __restrict__ WtFc,
            unsigned short* __restrict__ WhF, const float* __restrict__ U,
            float* __restrict__ Wh1, float* __restrict__ Wh2) {
    __shared__ unsigned short bbuf[2][8192];  // 16 KB per buffer
    int blk = blockIdx.x;
    int b  = blk >> 4;
    int r0 = (blk & 15) * 64;
    int t = threadIdx.x;
    int w = t >> 6;
    int lane = t & 63;
    int quad = lane >> 4, m16 = lane & 15;
    int rowb = r0 + w * 16;

    int l0 = l[2 * b], l1 = l[2 * b + 1];
    bool allI = (l0 <= r0) && (r0 + 64 <= l1);
    bool allC = (l1 <= r0) || (l0 >= r0 + 64);
    int npass = (allI || allC) ? 1 : 2;

    int row = rowb + m16;
    bool sel = (row >= l0) && (row < l1);
    const float* xrow = inp + ((size_t)(b * N_ + row)) * H_;
    const float* u1 = U + (sel ? 0 : H_);
    const float* u2 = U + 2 * H_ + (sel ? 0 : H_);

    // score-dot pre-loop (xrow re-read in main loop hits cache)
    float d1 = 0.f, d2 = 0.f;
#pragma unroll 2
    for (int ks = 0; ks < 8; ++ks) {
        const float4 xa = *reinterpret_cast<const float4*>(xrow + ks * 32 + quad * 8);
        const float4 xb = *reinterpret_cast<const float4*>(xrow + ks * 32 + quad * 8 + 4);
        const float4 ua = *reinterpret_cast<const float4*>(u1 + ks * 32 + quad * 8);
        const float4 ub = *reinterpret_cast<const float4*>(u1 + ks * 32 + quad * 8 + 4);
        const float4 va = *reinterpret_cast<const float4*>(u2 + ks * 32 + quad * 8);
        const float4 vb = *reinterpret_cast<const float4*>(u2 + ks * 32 + quad * 8 + 4);
        d1 += xa.x * ua.x + xa.y * ua.y + xa.z * ua.z + xa.w * ua.w
            + xb.x * ub.x + xb.y * ub.y + xb.z * ub.z + xb.w * ub.w;
        d2 += xa.x * va.x + xa.y * va.y + xa.z * va.z + xa.w * va.w
            + xb.x * vb.x + xb.y * vb.y + xb.z * vb.z + xb.w * vb.w;
    }
    d1 += __shfl_xor(d1, 16); d1 += __shfl_xor(d1, 32);
    d2 += __shfl_xor(d2, 16); d2 += __shfl_xor(d2, 32);
    if (quad == 0) {
        Wh1[b * N_ + rowb + m16] = d1;
        Wh2[b * N_ + rowb + m16] = d2;
    }

    unsigned short* fb = WhF + (size_t)b * (N_ * H_);
    int j0 = rowb + quad * 4;
    int ksO = j0 >> 5;
    int laneF = m16 + 16 * ((j0 & 31) >> 3);
    int jj0 = j0 & 7;

    for (int pass = 0; pass < npass; ++pass) {
        const unsigned short* gbase =
            (npass == 1) ? (allI ? WtFi : WtFc) : (pass == 0 ? WtFi : WtFc);

        floatx4 acc[16];
#pragma unroll
        for (int c = 0; c < 16; ++c) acc[c] = (floatx4){0.f, 0.f, 0.f, 0.f};

        {   // prologue: stage ks=0, conflict-free 16 B/thread x 4 chunks
#pragma unroll
            for (int j = 0; j < 4; ++j)
                *reinterpret_cast<uint4*>(&bbuf[0][j * 2048 + t * 8]) =
                    *reinterpret_cast<const uint4*>(gbase + j * 2048 + t * 8);
        }
        for (int ks = 0; ks < 8; ++ks) {
            __syncthreads();
            uint4 v[4];
            if (ks < 7) {
                const unsigned short* sn = gbase + (size_t)(ks + 1) * 8192;
#pragma unroll
                for (int j = 0; j < 4; ++j)
                    v[j] = *reinterpret_cast<const uint4*>(sn + j * 2048 + t * 8);
            }
            const float4 xa = *reinterpret_cast<const float4*>(xrow + ks * 32 + quad * 8);
            const float4 xb = *reinterpret_cast<const float4*>(xrow + ks * 32 + quad * 8 + 4);
            unsigned int pk0 = (unsigned int)f2bs(xa.x) | ((unsigned int)f2bs(xa.y) << 16);
            unsigned int pk1 = (unsigned int)f2bs(xa.z) | ((unsigned int)f2bs(xa.w) << 16);
            unsigned int pk2 = (unsigned int)f2bs(xb.x) | ((unsigned int)f2bs(xb.y) << 16);
            unsigned int pk3 = (unsigned int)f2bs(xb.z) | ((unsigned int)f2bs(xb.w) << 16);
            uint4 apk = {pk0, pk1, pk2, pk3};
            bf16x8 af = __builtin_bit_cast(bf16x8, apk);

            const unsigned short* bptr = &bbuf[ks & 1][lane * 8];
#pragma unroll
            for (int c = 0; c < 16; ++c) {
                bf16x8 bfr = *reinterpret_cast<const bf16x8*>(bptr + c * 512);
                acc[c] = __builtin_amdgcn_mfma_f32_16x16x32_bf16(af, bfr, acc[c], 0, 0, 0);
            }
            if (ks < 7) {
#pragma unroll
                for (int j = 0; j < 4; ++j)
                    *reinterpret_cast<uint4*>(&bbuf[(ks + 1) & 1][j * 2048 + t * 8]) = v[j];
            }
        }
        __syncthreads();

#pragma unroll
        for (int c = 0; c < 16; ++c) {
            size_t base = ((size_t)((ksO * 16 + c) * 64) + laneF) * 8 + jj0;
            if (npass == 1) {
                unsigned int lo = (unsigned int)f2bs(acc[c][0]) | ((unsigned int)f2bs(acc[c][1]) << 16);
                unsigned int hi = (unsigned int)f2bs(acc[c][2]) | ((unsigned int)f2bs(acc[c][3]) << 16);
                uint2 v2 = {lo, hi};
                *reinterpret_cast<uint2*>(fb + base) = v2;
            } else {
                bool want[4]; bool all = true, none = true;
#pragma unroll
                for (int r = 0; r < 4; ++r) {
                    int j = j0 + r;
                    bool s2 = (j >= l0) && (j < l1);
                    want[r] = (pass == 0) ? s2 : !s2;
                    all = all && want[r]; none = none && !want[r];
                }
                if (all) {
                    unsigned int lo = (unsigned int)f2bs(acc[c][0]) | ((unsigned int)f2bs(acc[c][1]) << 16);
                    unsigned int hi = (unsigned int)f2bs(acc[c][2]) | ((unsigned int)f2bs(acc[c][3]) << 16);
                    uint2 v2 = {lo, hi};
                    *reinterpret_cast<uint2*>(fb + base) = v2;
                } else if (!none) {
#pragma unroll
                    for (int r = 0; r < 4; ++r)
                        if (want[r]) fb[base + r] = f2bs(acc[c][r]);
                }
            }
        }
    }
}

// ---------------------------------------------------------------------------
// k_attn: fused masked-softmax + P@Wh (MFMA) + elu. Unchanged from R4
// (mask-based phase 1, fp32 shuffle row sums, 1-step register prefetch in
// the ks loop). Estimated ~48 us from R4 cross-round arithmetic.
// Grid = B*(N/32) = 1024, XCD-swizzled, 2 blocks/CU.
// ---------------------------------------------------------------------------
__global__ __launch_bounds__(256)
void k_attn(const unsigned int* __restrict__ Mask, const float* __restrict__ Wh1,
            const float* __restrict__ Wh2, const unsigned short* __restrict__ WhF,
            float* __restrict__ out) {
    __shared__ unsigned short pfrag[2][32 * PF_PITCH];  // 2 x 33,280 B
    __shared__ float rsum[2][16];
    int t = threadIdx.x, w = t >> 6, lane = t & 63;
    int bi = blockIdx.x;
    int b = (bi & 7) * 4 + (bi >> 8);   // XCD-swizzle
    int tile = (bi >> 3) & 31;
    int rowbase = tile * 32;

    const float* Wh2b = Wh2 + b * N_;
    float4 w2v[4];
#pragma unroll
    for (int ch = 0; ch < 4; ++ch)
        w2v[ch] = *reinterpret_cast<const float4*>(Wh2b + ch * 256 + lane * 4);

    int ksl = lane >> 3;
    int q2 = (lane >> 1) & 3;
    int jj0 = (lane & 1) * 4;
    int d  = lane >> 5;    // mask dword select
    int lb = lane & 31;    // mask bit select

#pragma unroll
    for (int tt = 0; tt < 2; ++tt) {
#pragma unroll
        for (int q = 0; q < 4; ++q) {
            int m = w * 4 + q;                 // row within 16-tile
            int i = rowbase + tt * 16 + m;
            float wh1 = Wh1[b * N_ + i];
            // wave-uniform mask row: 32 dwords = 16 x uint2
            const uint2* Mrow = reinterpret_cast<const uint2*>(
                Mask + ((size_t)(b * N_ + i)) * 32);
            unsigned int wv[4][4];
#pragma unroll
            for (int ch = 0; ch < 4; ++ch)
#pragma unroll
                for (int c = 0; c < 4; ++c) {
                    uint2 u = Mrow[ch * 4 + c];
                    wv[ch][c] = d ? u.y : u.x;
                }
            // swizzled slot address (matches phase-2 read swizzle)
            int s = m + 16 * q2;
            int sw = s ^ ((s >> 3) & 7);
            int sls = sw * 8 + jj0;
            float rp = 0.f;
#pragma unroll
            for (int ch = 0; ch < 4; ++ch) {
                float aa[4];
#pragma unroll
                for (int c = 0; c < 4; ++c)
                    aa[c] = (float)((wv[ch][c] >> lb) & 1u);
                if ((i >> 2) == (ch * 64 + lane)) aa[i & 3] += 1.0f;  // A + I
                float ww[4] = {w2v[ch].x, w2v[ch].y, w2v[ch].z, w2v[ch].w};
                float p[4];
#pragma unroll
                for (int c = 0; c < 4; ++c) {
                    float e  = (wh1 + ww[c]) * aa[c];
                    float lv = fmaxf(e, 0.2f * e);          // leaky_relu
                    p[c] = aa[c] > 0.f ? __expf(lv) : 0.f;  // no max-subtraction
                }
                rp += (p[0] + p[1]) + (p[2] + p[3]);
                unsigned int lo = (unsigned int)f2bs(p[0]) | ((unsigned int)f2bs(p[1]) << 16);
                unsigned int hi = (unsigned int)f2bs(p[2]) | ((unsigned int)f2bs(p[3]) << 16);
                uint2 v = {lo, hi};
                int ks = ch * 8 + ksl;
                *reinterpret_cast<uint2*>(pfrag[tt] + ks * PF_PITCH + sls) = v;
            }
            // fp32 softmax denominator: full 64-lane reduce
            for (int off = 32; off; off >>= 1) rp += __shfl_xor(rp, off);
            if (lane == 0) rsum[tt][m] = rp;
        }
    }
    __syncthreads();

    // Phase 2: P[32 x 1024] @ Wh[1024 x 256] with 1-step register prefetch.
    const unsigned short* WB = WhF + (size_t)b * (N_ * H_);
    int rs = (lane ^ ((lane >> 3) & 7)) * 8;   // swizzled read offset (shorts)
    floatx4 acc0[4], acc1[4];
#pragma unroll
    for (int cc = 0; cc < 4; ++cc) {
        acc0[cc] = (floatx4){0.f, 0.f, 0.f, 0.f};
        acc1[cc] = (floatx4){0.f, 0.f, 0.f, 0.f};
    }
    bf16x8 af0 = *reinterpret_cast<const bf16x8*>(pfrag[0] + rs);
    bf16x8 af1 = *reinterpret_cast<const bf16x8*>(pfrag[1] + rs);
    bf16x8 bfv[4];
#pragma unroll
    for (int cc = 0; cc < 4; ++cc)
        bfv[cc] = *reinterpret_cast<const bf16x8*>(
            WB + ((size_t)((w * 4 + cc) * 64 + lane)) * 8);
    for (int ks = 0; ks < 32; ++ks) {
        bf16x8 naf0, naf1, nbf[4];
        if (ks < 31) {
            naf0 = *reinterpret_cast<const bf16x8*>(pfrag[0] + (ks + 1) * PF_PITCH + rs);
            naf1 = *reinterpret_cast<const bf16x8*>(pfrag[1] + (ks + 1) * PF_PITCH + rs);
#pragma unroll
            for (int cc = 0; cc < 4; ++cc)
                nbf[cc] = *reinterpret_cast<const bf16x8*>(
                    WB + ((size_t)(((ks + 1) * 16 + w * 4 + cc) * 64 + lane)) * 8);
        }
#pragma unroll
        for (int cc = 0; cc < 4; ++cc) {
            acc0[cc] = __builtin_amdgcn_mfma_f32_16x16x32_bf16(af0, bfv[cc], acc0[cc], 0, 0, 0);
            acc1[cc] = __builtin_amdgcn_mfma_f32_16x16x32_bf16(af1, bfv[cc], acc1[cc], 0, 0, 0);
        }
        if (ks < 31) {
            af0 = naf0; af1 = naf1;
#pragma unroll
            for (int cc = 0; cc < 4; ++cc) bfv[cc] = nbf[cc];
        }
    }

    // Epilogue: normalize (fp32 sums from LDS), elu, store.
    int quad = lane >> 4, m16 = lane & 15;
    float inv0[4], inv1[4];
#pragma unroll
    for (int r = 0; r < 4; ++r) {
        inv0[r] = 1.0f / rsum[0][quad * 4 + r];
        inv1[r] = 1.0f / rsum[1][quad * 4 + r];
    }
#pragma unroll
    for (int cc = 0; cc < 4; ++cc) {
        int col = (w * 4 + cc) * 16 + m16;
#pragma unroll
        for (int r = 0; r < 4; ++r) {
            int m = quad * 4 + r;
            float v0 = acc0[cc][r] * inv0[r];
            v0 = v0 > 0.f ? v0 : __expf(v0) - 1.0f;
            out[((size_t)(b * N_ + rowbase + m)) * H_ + col] = v0;
            float v1 = acc1[cc][r] * inv1[r];
            v1 = v1 > 0.f ? v1 : __expf(v1) - 1.0f;
            out[((size_t)(b * N_ + rowbase + 16 + m)) * H_ + col] = v1;
        }
    }
}

// ---------------------------------------------------------------------------
extern "C" void kernel_launch(void* const* d_in, const int* in_sizes, int n_in,
                              void* d_out, int out_size, void* d_ws, size_t ws_size,
                              hipStream_t stream) {
    const float* inp = (const float*)d_in[0];
    const float* A   = (const float*)d_in[1];
    const int*   l   = (const int*)d_in[2];
    const float* Wi  = (const float*)d_in[3];
    const float* Wc  = (const float*)d_in[4];
    const float* a   = (const float*)d_in[5];
    float* out = (float*)d_out;

    char* ws = (char*)d_ws;
    size_t off = 0;
    unsigned short* WhF  = (unsigned short*)(ws + off); off += (size_t)B_ * N_ * H_ * 2;
    float* Wh1 = (float*)(ws + off); off += (size_t)B_ * N_ * 4;
    float* Wh2 = (float*)(ws + off); off += (size_t)B_ * N_ * 4;
    float* U   = (float*)(ws + off); off += 4 * H_ * 4;
    unsigned short* WtFi = (unsigned short*)(ws + off); off += (size_t)H_ * H_ * 2;
    unsigned short* WtFc = (unsigned short*)(ws + off); off += (size_t)H_ * H_ * 2;
    unsigned int* Mask = (unsigned int*)(ws + off); off += (size_t)B_ * N_ * 32 * 4;

    k_pre<<<32 + H_, 256, 0, stream>>>(Wi, Wc, a, U, WtFi, WtFc);
    k_abits<<<(B_ * N_) / 16, 256, 0, stream>>>(A, Mask);
    k_gemm<<<B_ * 16, 256, 0, stream>>>(inp, l, WtFi, WtFc, WhF, U, Wh1, Wh2);
    k_attn<<<B_ * (N_ / 32), 256, 0, stream>>>(Mask, Wh1, Wh2, WhF, out);
}

// Round 6
// 295.104 us; speedup vs baseline: 1.0511x; 1.0160x over previous
//
#include <hip/hip_runtime.h>
#include <hip/hip_bf16.h>
#include <stdint.h>

#define B_ 32
#define N_ 1024
#define H_ 256
#define PF_PITCH 520   // shorts per ks row (1040 B -> +4 banks per ks, 16B-aligned)

typedef short bf16x8 __attribute__((ext_vector_type(8)));
typedef float floatx4 __attribute__((ext_vector_type(4)));

__device__ inline unsigned short f2bs(float x) {
    __hip_bfloat16 h = __float2bfloat16(x);
    return __builtin_bit_cast(unsigned short, h);
}

// ---------------------------------------------------------------------------
// k_pre = {prep (blocks 0..31)} U {uvec (blocks 32..287)}.
// prep: W -> fragment-ordered bf16 WtF. uvec: u = {Wi,Wc}^T @ {a1,a2}.
// ---------------------------------------------------------------------------
__global__ __launch_bounds__(256)
void k_pre(const float* __restrict__ Wi, const float* __restrict__ Wc,
           const float* __restrict__ a, float* __restrict__ U,
           unsigned short* __restrict__ WtFi, unsigned short* __restrict__ WtFc) {
    int bid = blockIdx.x;
    int t = threadIdx.x;
    if (bid < 32) {
        // ---- prep ----
        __shared__ float tile[64][65];   // [k_local][n_local]
        int mat = bid >> 4;
        int tr = ((bid >> 2) & 3) * 64;  // k-tile origin
        int tc = (bid & 3) * 64;         // n-tile origin
        const float* W = mat ? Wc : Wi;
        unsigned short* WtF = mat ? WtFc : WtFi;
        int rr = t >> 2, c4 = (t & 3) * 16;
        const float* src = W + (size_t)(tr + rr) * H_ + tc + c4;
#pragma unroll
        for (int j = 0; j < 4; ++j) {
            float4 v = *reinterpret_cast<const float4*>(src + j * 4);
            tile[rr][c4 + 4 * j + 0] = v.x;
            tile[rr][c4 + 4 * j + 1] = v.y;
            tile[rr][c4 + 4 * j + 2] = v.z;
            tile[rr][c4 + 4 * j + 3] = v.w;
        }
        __syncthreads();
#pragma unroll
        for (int h = 0; h < 2; ++h) {
            int s = h * 256 + t;
            int ksl = s >> 8;
            int cl  = (s >> 6) & 3;
            int ll  = s & 63;
            int m16v = ll & 15, quadv = ll >> 4;
            int nloc = cl * 16 + m16v;
            int kb = ksl * 32 + quadv * 8;
            unsigned int pk[4];
#pragma unroll
            for (int jj = 0; jj < 4; ++jj) {
                unsigned short lo = f2bs(tile[kb + 2 * jj][nloc]);
                unsigned short hi = f2bs(tile[kb + 2 * jj + 1][nloc]);
                pk[jj] = (unsigned int)lo | ((unsigned int)hi << 16);
            }
            int ksg = (tr >> 5) + ksl;
            int cg  = (tc >> 4) + cl;
            *reinterpret_cast<uint4*>(WtF + ((size_t)(ksg * 16 + cg) * 64 + ll) * 8) =
                *reinterpret_cast<uint4*>(pk);
        }
    } else {
        // ---- uvec ----
        int k = bid - 32;
        float wi = Wi[k * H_ + t];
        float wc = Wc[k * H_ + t];
        float a1 = a[t], a2 = a[H_ + t];
        float p0 = wi * a1, p1 = wc * a1, p2 = wi * a2, p3 = wc * a2;
        for (int off = 32; off; off >>= 1) {
            p0 += __shfl_xor(p0, off);
            p1 += __shfl_xor(p1, off);
            p2 += __shfl_xor(p2, off);
            p3 += __shfl_xor(p3, off);
        }
        __shared__ float red[4][4];
        int w = t >> 6;
        if ((t & 63) == 0) { red[w][0] = p0; red[w][1] = p1; red[w][2] = p2; red[w][3] = p3; }
        __syncthreads();
        if (t == 0) {
            U[0 * H_ + k] = red[0][0] + red[1][0] + red[2][0] + red[3][0];
            U[1 * H_ + k] = red[0][1] + red[1][1] + red[2][1] + red[3][1];
            U[2 * H_ + k] = red[0][2] + red[1][2] + red[2][2] + red[3][2];
            U[3 * H_ + k] = red[0][3] + red[1][3] + red[2][3] + red[3][3];
        }
    }
}

// ---------------------------------------------------------------------------
// k_abits: A (binary fp32, 134 MB) -> bitmask M (4 MB), BALLOT-FREE.
// Layout: M[row*32 + col/32], bit = col%32 (thread-private packing).
// Each thread owns one 32-col chunk of one row: 8 independent float4 loads
// (128 B in flight per thread, ~8 KB/wave MLP -> BW-bound, not latency-
// bound like the ballot version whose wave-wide dependency capped in-flight
// bytes at 64 B/wave). 8 rows/block, 4096 blocks, no LDS, no cross-lane.
// ---------------------------------------------------------------------------
__global__ __launch_bounds__(256)
void k_abits(const float* __restrict__ A, unsigned int* __restrict__ M) {
    int t = threadIdx.x;
    size_t row = (size_t)blockIdx.x * 8 + (t >> 5);
    int cd = t & 31;                       // 32-col chunk index
    const float* src = A + row * N_ + cd * 32;
    float4 v[8];
#pragma unroll
    for (int j = 0; j < 8; ++j)
        v[j] = *reinterpret_cast<const float4*>(src + j * 4);
    unsigned int bits = 0;
#pragma unroll
    for (int j = 0; j < 8; ++j) {
        bits |= (v[j].x > 0.f ? 1u : 0u) << (j * 4 + 0);
        bits |= (v[j].y > 0.f ? 1u : 0u) << (j * 4 + 1);
        bits |= (v[j].z > 0.f ? 1u : 0u) << (j * 4 + 2);
        bits |= (v[j].w > 0.f ? 1u : 0u) << (j * 4 + 3);
    }
    M[row * 32 + cd] = bits;
}

// ---------------------------------------------------------------------------
// k_gemm: Wh = inp @ W_sel(row) via MFMA, full 256-col tiles (one block =
// 64 rows x 256 cols, acc[16]). Conflict-free 16 B/thread x 4 chunk
// staging. Score-dots in a pre-loop. Grid 512.
// ---------------------------------------------------------------------------
__global__ __launch_bounds__(256, 2)
void k_gemm(const float* __restrict__ inp, const int* __restrict__ l,
            const unsigned short* __restrict__ WtFi, const unsigned short* __restrict__ WtFc,
            unsigned short* __restrict__ WhF, const float* __restrict__ U,
            float* __restrict__ Wh1, float* __restrict__ Wh2) {
    __shared__ unsigned short bbuf[2][8192];  // 16 KB per buffer
    int blk = blockIdx.x;
    int b  = blk >> 4;
    int r0 = (blk & 15) * 64;
    int t = threadIdx.x;
    int w = t >> 6;
    int lane = t & 63;
    int quad = lane >> 4, m16 = lane & 15;
    int rowb = r0 + w * 16;

    int l0 = l[2 * b], l1 = l[2 * b + 1];
    bool allI = (l0 <= r0) && (r0 + 64 <= l1);
    bool allC = (l1 <= r0) || (l0 >= r0 + 64);
    int npass = (allI || allC) ? 1 : 2;

    int row = rowb + m16;
    bool sel = (row >= l0) && (row < l1);
    const float* xrow = inp + ((size_t)(b * N_ + row)) * H_;
    const float* u1 = U + (sel ? 0 : H_);
    const float* u2 = U + 2 * H_ + (sel ? 0 : H_);

    // score-dot pre-loop (xrow re-read in main loop hits cache)
    float d1 = 0.f, d2 = 0.f;
#pragma unroll 2
    for (int ks = 0; ks < 8; ++ks) {
        const float4 xa = *reinterpret_cast<const float4*>(xrow + ks * 32 + quad * 8);
        const float4 xb = *reinterpret_cast<const float4*>(xrow + ks * 32 + quad * 8 + 4);
        const float4 ua = *reinterpret_cast<const float4*>(u1 + ks * 32 + quad * 8);
        const float4 ub = *reinterpret_cast<const float4*>(u1 + ks * 32 + quad * 8 + 4);
        const float4 va = *reinterpret_cast<const float4*>(u2 + ks * 32 + quad * 8);
        const float4 vb = *reinterpret_cast<const float4*>(u2 + ks * 32 + quad * 8 + 4);
        d1 += xa.x * ua.x + xa.y * ua.y + xa.z * ua.z + xa.w * ua.w
            + xb.x * ub.x + xb.y * ub.y + xb.z * ub.z + xb.w * ub.w;
        d2 += xa.x * va.x + xa.y * va.y + xa.z * va.z + xa.w * va.w
            + xb.x * vb.x + xb.y * vb.y + xb.z * vb.z + xb.w * vb.w;
    }
    d1 += __shfl_xor(d1, 16); d1 += __shfl_xor(d1, 32);
    d2 += __shfl_xor(d2, 16); d2 += __shfl_xor(d2, 32);
    if (quad == 0) {
        Wh1[b * N_ + rowb + m16] = d1;
        Wh2[b * N_ + rowb + m16] = d2;
    }

    unsigned short* fb = WhF + (size_t)b * (N_ * H_);
    int j0 = rowb + quad * 4;
    int ksO = j0 >> 5;
    int laneF = m16 + 16 * ((j0 & 31) >> 3);
    int jj0 = j0 & 7;

    for (int pass = 0; pass < npass; ++pass) {
        const unsigned short* gbase =
            (npass == 1) ? (allI ? WtFi : WtFc) : (pass == 0 ? WtFi : WtFc);

        floatx4 acc[16];
#pragma unroll
        for (int c = 0; c < 16; ++c) acc[c] = (floatx4){0.f, 0.f, 0.f, 0.f};

        {   // prologue: stage ks=0, conflict-free 16 B/thread x 4 chunks
#pragma unroll
            for (int j = 0; j < 4; ++j)
                *reinterpret_cast<uint4*>(&bbuf[0][j * 2048 + t * 8]) =
                    *reinterpret_cast<const uint4*>(gbase + j * 2048 + t * 8);
        }
        for (int ks = 0; ks < 8; ++ks) {
            __syncthreads();
            uint4 v[4];
            if (ks < 7) {
                const unsigned short* sn = gbase + (size_t)(ks + 1) * 8192;
#pragma unroll
                for (int j = 0; j < 4; ++j)
                    v[j] = *reinterpret_cast<const uint4*>(sn + j * 2048 + t * 8);
            }
            const float4 xa = *reinterpret_cast<const float4*>(xrow + ks * 32 + quad * 8);
            const float4 xb = *reinterpret_cast<const float4*>(xrow + ks * 32 + quad * 8 + 4);
            unsigned int pk0 = (unsigned int)f2bs(xa.x) | ((unsigned int)f2bs(xa.y) << 16);
            unsigned int pk1 = (unsigned int)f2bs(xa.z) | ((unsigned int)f2bs(xa.w) << 16);
            unsigned int pk2 = (unsigned int)f2bs(xb.x) | ((unsigned int)f2bs(xb.y) << 16);
            unsigned int pk3 = (unsigned int)f2bs(xb.z) | ((unsigned int)f2bs(xb.w) << 16);
            uint4 apk = {pk0, pk1, pk2, pk3};
            bf16x8 af = __builtin_bit_cast(bf16x8, apk);

            const unsigned short* bptr = &bbuf[ks & 1][lane * 8];
#pragma unroll
            for (int c = 0; c < 16; ++c) {
                bf16x8 bfr = *reinterpret_cast<const bf16x8*>(bptr + c * 512);
                acc[c] = __builtin_amdgcn_mfma_f32_16x16x32_bf16(af, bfr, acc[c], 0, 0, 0);
            }
            if (ks < 7) {
#pragma unroll
                for (int j = 0; j < 4; ++j)
                    *reinterpret_cast<uint4*>(&bbuf[(ks + 1) & 1][j * 2048 + t * 8]) = v[j];
            }
        }
        __syncthreads();

#pragma unroll
        for (int c = 0; c < 16; ++c) {
            size_t base = ((size_t)((ksO * 16 + c) * 64) + laneF) * 8 + jj0;
            if (npass == 1) {
                unsigned int lo = (unsigned int)f2bs(acc[c][0]) | ((unsigned int)f2bs(acc[c][1]) << 16);
                unsigned int hi = (unsigned int)f2bs(acc[c][2]) | ((unsigned int)f2bs(acc[c][3]) << 16);
                uint2 v2 = {lo, hi};
                *reinterpret_cast<uint2*>(fb + base) = v2;
            } else {
                bool want[4]; bool all = true, none = true;
#pragma unroll
                for (int r = 0; r < 4; ++r) {
                    int j = j0 + r;
                    bool s2 = (j >= l0) && (j < l1);
                    want[r] = (pass == 0) ? s2 : !s2;
                    all = all && want[r]; none = none && !want[r];
                }
                if (all) {
                    unsigned int lo = (unsigned int)f2bs(acc[c][0]) | ((unsigned int)f2bs(acc[c][1]) << 16);
                    unsigned int hi = (unsigned int)f2bs(acc[c][2]) | ((unsigned int)f2bs(acc[c][3]) << 16);
                    uint2 v2 = {lo, hi};
                    *reinterpret_cast<uint2*>(fb + base) = v2;
                } else if (!none) {
#pragma unroll
                    for (int r = 0; r < 4; ++r)
                        if (want[r]) fb[base + r] = f2bs(acc[c][r]);
                }
            }
        }
    }
}

// ---------------------------------------------------------------------------
// k_attn: fused masked-softmax + P@Wh (MFMA) + elu. R4 structure; phase 1
// updated to the new thread-private mask layout: lane's 4 bits for chunk ch
// sit at dword Mrow[ch*8 + (lane>>3)], shift (lane&7)*4 -- 4 per-lane loads
// per row instead of 16 wave-uniform uint2s.
// Grid = B*(N/32) = 1024, XCD-swizzled, 2 blocks/CU.
// ---------------------------------------------------------------------------
__global__ __launch_bounds__(256)
void k_attn(const unsigned int* __restrict__ Mask, const float* __restrict__ Wh1,
            const float* __restrict__ Wh2, const unsigned short* __restrict__ WhF,
            float* __restrict__ out) {
    __shared__ unsigned short pfrag[2][32 * PF_PITCH];  // 2 x 33,280 B
    __shared__ float rsum[2][16];
    int t = threadIdx.x, w = t >> 6, lane = t & 63;
    int bi = blockIdx.x;
    int b = (bi & 7) * 4 + (bi >> 8);   // XCD-swizzle
    int tile = (bi >> 3) & 31;
    int rowbase = tile * 32;

    const float* Wh2b = Wh2 + b * N_;
    float4 w2v[4];
#pragma unroll
    for (int ch = 0; ch < 4; ++ch)
        w2v[ch] = *reinterpret_cast<const float4*>(Wh2b + ch * 256 + lane * 4);

    int ksl = lane >> 3;
    int q2 = (lane >> 1) & 3;
    int jj0 = (lane & 1) * 4;
    int mdw = lane >> 3;          // mask dword within chunk group
    int msh = (lane & 7) * 4;     // bit shift for this lane's 4 cols

#pragma unroll
    for (int tt = 0; tt < 2; ++tt) {
#pragma unroll
        for (int q = 0; q < 4; ++q) {
            int m = w * 4 + q;                 // row within 16-tile
            int i = rowbase + tt * 16 + m;
            float wh1 = Wh1[b * N_ + i];
            const unsigned int* Mrow = Mask + ((size_t)(b * N_ + i)) * 32;
            unsigned int mr[4];
#pragma unroll
            for (int ch = 0; ch < 4; ++ch)
                mr[ch] = Mrow[ch * 8 + mdw];
            // swizzled slot address (matches phase-2 read swizzle)
            int s = m + 16 * q2;
            int sw = s ^ ((s >> 3) & 7);
            int sls = sw * 8 + jj0;
            float rp = 0.f;
#pragma unroll
            for (int ch = 0; ch < 4; ++ch) {
                float aa[4];
#pragma unroll
                for (int c = 0; c < 4; ++c)
                    aa[c] = (float)((mr[ch] >> (msh + c)) & 1u);
                if ((i >> 2) == (ch * 64 + lane)) aa[i & 3] += 1.0f;  // A + I
                float ww[4] = {w2v[ch].x, w2v[ch].y, w2v[ch].z, w2v[ch].w};
                float p[4];
#pragma unroll
                for (int c = 0; c < 4; ++c) {
                    float e  = (wh1 + ww[c]) * aa[c];
                    float lv = fmaxf(e, 0.2f * e);          // leaky_relu
                    p[c] = aa[c] > 0.f ? __expf(lv) : 0.f;  // no max-subtraction
                }
                rp += (p[0] + p[1]) + (p[2] + p[3]);
                unsigned int lo = (unsigned int)f2bs(p[0]) | ((unsigned int)f2bs(p[1]) << 16);
                unsigned int hi = (unsigned int)f2bs(p[2]) | ((unsigned int)f2bs(p[3]) << 16);
                uint2 v = {lo, hi};
                int ks = ch * 8 + ksl;
                *reinterpret_cast<uint2*>(pfrag[tt] + ks * PF_PITCH + sls) = v;
            }
            // fp32 softmax denominator: full 64-lane reduce
            for (int off = 32; off; off >>= 1) rp += __shfl_xor(rp, off);
            if (lane == 0) rsum[tt][m] = rp;
        }
    }
    __syncthreads();

    // Phase 2: P[32 x 1024] @ Wh[1024 x 256] with 1-step register prefetch.
    const unsigned short* WB = WhF + (size_t)b * (N_ * H_);
    int rs = (lane ^ ((lane >> 3) & 7)) * 8;   // swizzled read offset (shorts)
    floatx4 acc0[4], acc1[4];
#pragma unroll
    for (int cc = 0; cc < 4; ++cc) {
        acc0[cc] = (floatx4){0.f, 0.f, 0.f, 0.f};
        acc1[cc] = (floatx4){0.f, 0.f, 0.f, 0.f};
    }
    bf16x8 af0 = *reinterpret_cast<const bf16x8*>(pfrag[0] + rs);
    bf16x8 af1 = *reinterpret_cast<const bf16x8*>(pfrag[1] + rs);
    bf16x8 bfv[4];
#pragma unroll
    for (int cc = 0; cc < 4; ++cc)
        bfv[cc] = *reinterpret_cast<const bf16x8*>(
            WB + ((size_t)((w * 4 + cc) * 64 + lane)) * 8);
    for (int ks = 0; ks < 32; ++ks) {
        bf16x8 naf0, naf1, nbf[4];
        if (ks < 31) {
            naf0 = *reinterpret_cast<const bf16x8*>(pfrag[0] + (ks + 1) * PF_PITCH + rs);
            naf1 = *reinterpret_cast<const bf16x8*>(pfrag[1] + (ks + 1) * PF_PITCH + rs);
#pragma unroll
            for (int cc = 0; cc < 4; ++cc)
                nbf[cc] = *reinterpret_cast<const bf16x8*>(
                    WB + ((size_t)(((ks + 1) * 16 + w * 4 + cc) * 64 + lane)) * 8);
        }
#pragma unroll
        for (int cc = 0; cc < 4; ++cc) {
            acc0[cc] = __builtin_amdgcn_mfma_f32_16x16x32_bf16(af0, bfv[cc], acc0[cc], 0, 0, 0);
            acc1[cc] = __builtin_amdgcn_mfma_f32_16x16x32_bf16(af1, bfv[cc], acc1[cc], 0, 0, 0);
        }
        if (ks < 31) {
            af0 = naf0; af1 = naf1;
#pragma unroll
            for (int cc = 0; cc < 4; ++cc) bfv[cc] = nbf[cc];
        }
    }

    // Epilogue: normalize (fp32 sums from LDS), elu, store.
    int quad = lane >> 4, m16 = lane & 15;
    float inv0[4], inv1[4];
#pragma unroll
    for (int r = 0; r < 4; ++r) {
        inv0[r] = 1.0f / rsum[0][quad * 4 + r];
        inv1[r] = 1.0f / rsum[1][quad * 4 + r];
    }
#pragma unroll
    for (int cc = 0; cc < 4; ++cc) {
        int col = (w * 4 + cc) * 16 + m16;
#pragma unroll
        for (int r = 0; r < 4; ++r) {
            int m = quad * 4 + r;
            float v0 = acc0[cc][r] * inv0[r];
            v0 = v0 > 0.f ? v0 : __expf(v0) - 1.0f;
            out[((size_t)(b * N_ + rowbase + m)) * H_ + col] = v0;
            float v1 = acc1[cc][r] * inv1[r];
            v1 = v1 > 0.f ? v1 : __expf(v1) - 1.0f;
            out[((size_t)(b * N_ + rowbase + 16 + m)) * H_ + col] = v1;
        }
    }
}

// ---------------------------------------------------------------------------
extern "C" void kernel_launch(void* const* d_in, const int* in_sizes, int n_in,
                              void* d_out, int out_size, void* d_ws, size_t ws_size,
                              hipStream_t stream) {
    const float* inp = (const float*)d_in[0];
    const float* A   = (const float*)d_in[1];
    const int*   l   = (const int*)d_in[2];
    const float* Wi  = (const float*)d_in[3];
    const float* Wc  = (const float*)d_in[4];
    const float* a   = (const float*)d_in[5];
    float* out = (float*)d_out;

    char* ws = (char*)d_ws;
    size_t off = 0;
    unsigned short* WhF  = (unsigned short*)(ws + off); off += (size_t)B_ * N_ * H_ * 2;
    float* Wh1 = (float*)(ws + off); off += (size_t)B_ * N_ * 4;
    float* Wh2 = (float*)(ws + off); off += (size_t)B_ * N_ * 4;
    float* U   = (float*)(ws + off); off += 4 * H_ * 4;
    unsigned short* WtFi = (unsigned short*)(ws + off); off += (size_t)H_ * H_ * 2;
    unsigned short* WtFc = (unsigned short*)(ws + off); off += (size_t)H_ * H_ * 2;
    unsigned int* Mask = (unsigned int*)(ws + off); off += (size_t)B_ * N_ * 32 * 4;

    k_pre<<<32 + H_, 256, 0, stream>>>(Wi, Wc, a, U, WtFi, WtFc);
    k_abits<<<(B_ * N_) / 8, 256, 0, stream>>>(A, Mask);
    k_gemm<<<B_ * 16, 256, 0, stream>>>(inp, l, WtFi, WtFc, WhF, U, Wh1, Wh2);
    k_attn<<<B_ * (N_ / 32), 256, 0, stream>>>(Mask, Wh1, Wh2, WhF, out);
}

// Round 9
// 289.777 us; speedup vs baseline: 1.0705x; 1.0184x over previous
//
#include <hip/hip_runtime.h>
#include <hip/hip_bf16.h>
#include <stdint.h>

#define B_ 32
#define N_ 1024
#define H_ 256
#define PF_PITCH 520   // shorts per ks row (1040 B -> +4 banks per ks, 16B-aligned)

typedef short bf16x8 __attribute__((ext_vector_type(8)));
typedef float floatx4 __attribute__((ext_vector_type(4)));

__device__ inline unsigned short f2bs(float x) {
    __hip_bfloat16 h = __float2bfloat16(x);
    return __builtin_bit_cast(unsigned short, h);
}

// ---------------------------------------------------------------------------
// k_pre = {prep (blocks 0..31)} U {uvec (blocks 32..287)}. (R6 verbatim)
// ---------------------------------------------------------------------------
__global__ __launch_bounds__(256)
void k_pre(const float* __restrict__ Wi, const float* __restrict__ Wc,
           const float* __restrict__ a, float* __restrict__ U,
           unsigned short* __restrict__ WtFi, unsigned short* __restrict__ WtFc) {
    int bid = blockIdx.x;
    int t = threadIdx.x;
    if (bid < 32) {
        __shared__ float tile[64][65];   // [k_local][n_local]
        int mat = bid >> 4;
        int tr = ((bid >> 2) & 3) * 64;  // k-tile origin
        int tc = (bid & 3) * 64;         // n-tile origin
        const float* W = mat ? Wc : Wi;
        unsigned short* WtF = mat ? WtFc : WtFi;
        int rr = t >> 2, c4 = (t & 3) * 16;
        const float* src = W + (size_t)(tr + rr) * H_ + tc + c4;
#pragma unroll
        for (int j = 0; j < 4; ++j) {
            float4 v = *reinterpret_cast<const float4*>(src + j * 4);
            tile[rr][c4 + 4 * j + 0] = v.x;
            tile[rr][c4 + 4 * j + 1] = v.y;
            tile[rr][c4 + 4 * j + 2] = v.z;
            tile[rr][c4 + 4 * j + 3] = v.w;
        }
        __syncthreads();
#pragma unroll
        for (int h = 0; h < 2; ++h) {
            int s = h * 256 + t;
            int ksl = s >> 8;
            int cl  = (s >> 6) & 3;
            int ll  = s & 63;
            int m16v = ll & 15, quadv = ll >> 4;
            int nloc = cl * 16 + m16v;
            int kb = ksl * 32 + quadv * 8;
            unsigned int pk[4];
#pragma unroll
            for (int jj = 0; jj < 4; ++jj) {
                unsigned short lo = f2bs(tile[kb + 2 * jj][nloc]);
                unsigned short hi = f2bs(tile[kb + 2 * jj + 1][nloc]);
                pk[jj] = (unsigned int)lo | ((unsigned int)hi << 16);
            }
            int ksg = (tr >> 5) + ksl;
            int cg  = (tc >> 4) + cl;
            *reinterpret_cast<uint4*>(WtF + ((size_t)(ksg * 16 + cg) * 64 + ll) * 8) =
                *reinterpret_cast<uint4*>(pk);
        }
    } else {
        int k = bid - 32;
        float wi = Wi[k * H_ + t];
        float wc = Wc[k * H_ + t];
        float a1 = a[t], a2 = a[H_ + t];
        float p0 = wi * a1, p1 = wc * a1, p2 = wi * a2, p3 = wc * a2;
        for (int off = 32; off; off >>= 1) {
            p0 += __shfl_xor(p0, off);
            p1 += __shfl_xor(p1, off);
            p2 += __shfl_xor(p2, off);
            p3 += __shfl_xor(p3, off);
        }
        __shared__ float red[4][4];
        int w = t >> 6;
        if ((t & 63) == 0) { red[w][0] = p0; red[w][1] = p1; red[w][2] = p2; red[w][3] = p3; }
        __syncthreads();
        if (t == 0) {
            U[0 * H_ + k] = red[0][0] + red[1][0] + red[2][0] + red[3][0];
            U[1 * H_ + k] = red[0][1] + red[1][1] + red[2][1] + red[3][1];
            U[2 * H_ + k] = red[0][2] + red[1][2] + red[2][2] + red[3][2];
            U[3 * H_ + k] = red[0][3] + red[1][3] + red[2][3] + red[3][3];
        }
    }
}

// ---------------------------------------------------------------------------
// k_abits: A (binary fp32, 134 MB) -> bitmask M (4 MB), ballot-free.
// (R6 verbatim: thread-private 32-col chunk, 8x float4 MLP, no LDS.)
// ---------------------------------------------------------------------------
__global__ __launch_bounds__(256)
void k_abits(const float* __restrict__ A, unsigned int* __restrict__ M) {
    int t = threadIdx.x;
    size_t row = (size_t)blockIdx.x * 8 + (t >> 5);
    int cd = t & 31;                       // 32-col chunk index
    const float* src = A + row * N_ + cd * 32;
    float4 v[8];
#pragma unroll
    for (int j = 0; j < 8; ++j)
        v[j] = *reinterpret_cast<const float4*>(src + j * 4);
    unsigned int bits = 0;
#pragma unroll
    for (int j = 0; j < 8; ++j) {
        bits |= (v[j].x > 0.f ? 1u : 0u) << (j * 4 + 0);
        bits |= (v[j].y > 0.f ? 1u : 0u) << (j * 4 + 1);
        bits |= (v[j].z > 0.f ? 1u : 0u) << (j * 4 + 2);
        bits |= (v[j].w > 0.f ? 1u : 0u) << (j * 4 + 3);
    }
    M[row * 32 + cd] = bits;
}

// ---------------------------------------------------------------------------
// k_gemm: REVERTED to the R0-measured structure (part of the solid
// F+gemm0+pre0=192 anchor): one block = 64 rows x 128 cols, score-dots
// fused in the K-loop, 8 KB double-buffered staging, grid B_*16*2 = 1024.
// Single-variable experiment vs R6: if R5's merged-256-col gemm was the
// regression, this alone recovers ~20-25 us.
// ---------------------------------------------------------------------------
__global__ __launch_bounds__(256)
void k_gemm(const float* __restrict__ inp, const int* __restrict__ l,
            const unsigned short* __restrict__ WtFi, const unsigned short* __restrict__ WtFc,
            unsigned short* __restrict__ WhF, const float* __restrict__ U,
            float* __restrict__ Wh1, float* __restrict__ Wh2) {
    __shared__ unsigned short bbuf[2][4096];  // 8 KB per buffer
    int blk = blockIdx.x;
    int b  = blk >> 5;
    int r0 = ((blk >> 1) & 15) * 64;
    int n0 = (blk & 1) * 128;
    int t = threadIdx.x;
    int w = t >> 6;
    int lane = t & 63;
    int quad = lane >> 4, m16 = lane & 15;
    int rowb = r0 + w * 16;

    int l0 = l[2 * b], l1 = l[2 * b + 1];
    bool allI = (l0 <= r0) && (r0 + 64 <= l1);
    bool allC = (l1 <= r0) || (l0 >= r0 + 64);
    int npass = (allI || allC) ? 1 : 2;

    int row = rowb + m16;
    bool sel = (row >= l0) && (row < l1);
    const float* xrow = inp + ((size_t)(b * N_ + row)) * H_;
    const float* u1 = U + (sel ? 0 : H_);
    const float* u2 = U + 2 * H_ + (sel ? 0 : H_);
    bool doWh = (n0 == 0);
    float d1 = 0.f, d2 = 0.f;

    unsigned short* fb = WhF + (size_t)b * (N_ * H_);
    int cb = n0 >> 4;   // 0 or 8

    int j0 = rowb + quad * 4;
    int ksO = j0 >> 5;
    int laneF = m16 + 16 * ((j0 & 31) >> 3);
    int jj0 = j0 & 7;

    for (int pass = 0; pass < npass; ++pass) {
        const unsigned short* WtF =
            (npass == 1) ? (allI ? WtFi : WtFc) : (pass == 0 ? WtFi : WtFc);
        const unsigned short* gbase = WtF + cb * 512;

        floatx4 acc[8];
#pragma unroll
        for (int c = 0; c < 8; ++c) acc[c] = (floatx4){0.f, 0.f, 0.f, 0.f};

        {   // prologue: stage ks=0 into buf0 (linear 8 KB copy)
            uint4 v0 = *reinterpret_cast<const uint4*>(gbase + (size_t)t * 8);
            uint4 v1 = *reinterpret_cast<const uint4*>(gbase + (size_t)(256 + t) * 8);
            *reinterpret_cast<uint4*>(&bbuf[0][t * 8]) = v0;
            *reinterpret_cast<uint4*>(&bbuf[0][(256 + t) * 8]) = v1;
        }
        for (int ks = 0; ks < 8; ++ks) {
            __syncthreads();
            uint4 v0, v1;
            if (ks < 7) {
                v0 = *reinterpret_cast<const uint4*>(gbase + (size_t)(ks + 1) * 8192 + t * 8);
                v1 = *reinterpret_cast<const uint4*>(gbase + (size_t)(ks + 1) * 8192 + (256 + t) * 8);
            }
            const float4 xa = *reinterpret_cast<const float4*>(xrow + ks * 32 + quad * 8);
            const float4 xb = *reinterpret_cast<const float4*>(xrow + ks * 32 + quad * 8 + 4);
            if (pass == 0 && doWh) {
                const float4 ua = *reinterpret_cast<const float4*>(u1 + ks * 32 + quad * 8);
                const float4 ub = *reinterpret_cast<const float4*>(u1 + ks * 32 + quad * 8 + 4);
                const float4 va = *reinterpret_cast<const float4*>(u2 + ks * 32 + quad * 8);
                const float4 vb = *reinterpret_cast<const float4*>(u2 + ks * 32 + quad * 8 + 4);
                d1 += xa.x * ua.x + xa.y * ua.y + xa.z * ua.z + xa.w * ua.w
                    + xb.x * ub.x + xb.y * ub.y + xb.z * ub.z + xb.w * ub.w;
                d2 += xa.x * va.x + xa.y * va.y + xa.z * va.z + xa.w * va.w
                    + xb.x * vb.x + xb.y * vb.y + xb.z * vb.z + xb.w * vb.w;
            }
            unsigned int pk0 = (unsigned int)f2bs(xa.x) | ((unsigned int)f2bs(xa.y) << 16);
            unsigned int pk1 = (unsigned int)f2bs(xa.z) | ((unsigned int)f2bs(xa.w) << 16);
            unsigned int pk2 = (unsigned int)f2bs(xb.x) | ((unsigned int)f2bs(xb.y) << 16);
            unsigned int pk3 = (unsigned int)f2bs(xb.z) | ((unsigned int)f2bs(xb.w) << 16);
            uint4 apk = {pk0, pk1, pk2, pk3};
            bf16x8 af = __builtin_bit_cast(bf16x8, apk);

            const unsigned short* bptr = &bbuf[ks & 1][lane * 8];
#pragma unroll
            for (int c = 0; c < 8; ++c) {
                bf16x8 bfr = *reinterpret_cast<const bf16x8*>(bptr + c * 512);
                acc[c] = __builtin_amdgcn_mfma_f32_16x16x32_bf16(af, bfr, acc[c], 0, 0, 0);
            }
            if (ks < 7) {
                *reinterpret_cast<uint4*>(&bbuf[(ks + 1) & 1][t * 8]) = v0;
                *reinterpret_cast<uint4*>(&bbuf[(ks + 1) & 1][(256 + t) * 8]) = v1;
            }
        }
        __syncthreads();

#pragma unroll
        for (int c = 0; c < 8; ++c) {
            size_t base = ((size_t)((ksO * 16 + cb + c) * 64) + laneF) * 8 + jj0;
            if (npass == 1) {
                unsigned int lo = (unsigned int)f2bs(acc[c][0]) | ((unsigned int)f2bs(acc[c][1]) << 16);
                unsigned int hi = (unsigned int)f2bs(acc[c][2]) | ((unsigned int)f2bs(acc[c][3]) << 16);
                uint2 v = {lo, hi};
                *reinterpret_cast<uint2*>(fb + base) = v;
            } else {
                bool want[4]; bool all = true, none = true;
#pragma unroll
                for (int r = 0; r < 4; ++r) {
                    int j = j0 + r;
                    bool s2 = (j >= l0) && (j < l1);
                    want[r] = (pass == 0) ? s2 : !s2;
                    all = all && want[r]; none = none && !want[r];
                }
                if (all) {
                    unsigned int lo = (unsigned int)f2bs(acc[c][0]) | ((unsigned int)f2bs(acc[c][1]) << 16);
                    unsigned int hi = (unsigned int)f2bs(acc[c][2]) | ((unsigned int)f2bs(acc[c][3]) << 16);
                    uint2 v = {lo, hi};
                    *reinterpret_cast<uint2*>(fb + base) = v;
                } else if (!none) {
#pragma unroll
                    for (int r = 0; r < 4; ++r)
                        if (want[r]) fb[base + r] = f2bs(acc[c][r]);
                }
            }
        }
    }

    if (doWh) {
        d1 += __shfl_xor(d1, 16); d1 += __shfl_xor(d1, 32);
        d2 += __shfl_xor(d2, 16); d2 += __shfl_xor(d2, 32);
        if (quad == 0) {
            Wh1[b * N_ + rowb + m16] = d1;
            Wh2[b * N_ + rowb + m16] = d2;
        }
    }
}

// ---------------------------------------------------------------------------
// k_attn: unchanged from R6 (mask phase 1, fp32 shuffle row sums, 1-step
// register prefetch). Grid = B*(N/32) = 1024, XCD-swizzled, 2 blocks/CU.
// ---------------------------------------------------------------------------
__global__ __launch_bounds__(256)
void k_attn(const unsigned int* __restrict__ Mask, const float* __restrict__ Wh1,
            const float* __restrict__ Wh2, const unsigned short* __restrict__ WhF,
            float* __restrict__ out) {
    __shared__ unsigned short pfrag[2][32 * PF_PITCH];  // 2 x 33,280 B
    __shared__ float rsum[2][16];
    int t = threadIdx.x, w = t >> 6, lane = t & 63;
    int bi = blockIdx.x;
    int b = (bi & 7) * 4 + (bi >> 8);   // XCD-swizzle
    int tile = (bi >> 3) & 31;
    int rowbase = tile * 32;

    const float* Wh2b = Wh2 + b * N_;
    float4 w2v[4];
#pragma unroll
    for (int ch = 0; ch < 4; ++ch)
        w2v[ch] = *reinterpret_cast<const float4*>(Wh2b + ch * 256 + lane * 4);

    int ksl = lane >> 3;
    int q2 = (lane >> 1) & 3;
    int jj0 = (lane & 1) * 4;
    int mdw = lane >> 3;          // mask dword within chunk group
    int msh = (lane & 7) * 4;     // bit shift for this lane's 4 cols

#pragma unroll
    for (int tt = 0; tt < 2; ++tt) {
#pragma unroll
        for (int q = 0; q < 4; ++q) {
            int m = w * 4 + q;                 // row within 16-tile
            int i = rowbase + tt * 16 + m;
            float wh1 = Wh1[b * N_ + i];
            const unsigned int* Mrow = Mask + ((size_t)(b * N_ + i)) * 32;
            unsigned int mr[4];
#pragma unroll
            for (int ch = 0; ch < 4; ++ch)
                mr[ch] = Mrow[ch * 8 + mdw];
            // swizzled slot address (matches phase-2 read swizzle)
            int s = m + 16 * q2;
            int sw = s ^ ((s >> 3) & 7);
            int sls = sw * 8 + jj0;
            float rp = 0.f;
#pragma unroll
            for (int ch = 0; ch < 4; ++ch) {
                float aa[4];
#pragma unroll
                for (int c = 0; c < 4; ++c)
                    aa[c] = (float)((mr[ch] >> (msh + c)) & 1u);
                if ((i >> 2) == (ch * 64 + lane)) aa[i & 3] += 1.0f;  // A + I
                float ww[4] = {w2v[ch].x, w2v[ch].y, w2v[ch].z, w2v[ch].w};
                float p[4];
#pragma unroll
                for (int c = 0; c < 4; ++c) {
                    float e  = (wh1 + ww[c]) * aa[c];
                    float lv = fmaxf(e, 0.2f * e);          // leaky_relu
                    p[c] = aa[c] > 0.f ? __expf(lv) : 0.f;  // no max-subtraction
                }
                rp += (p[0] + p[1]) + (p[2] + p[3]);
                unsigned int lo = (unsigned int)f2bs(p[0]) | ((unsigned int)f2bs(p[1]) << 16);
                unsigned int hi = (unsigned int)f2bs(p[2]) | ((unsigned int)f2bs(p[3]) << 16);
                uint2 v = {lo, hi};
                int ks = ch * 8 + ksl;
                *reinterpret_cast<uint2*>(pfrag[tt] + ks * PF_PITCH + sls) = v;
            }
            // fp32 softmax denominator: full 64-lane reduce
            for (int off = 32; off; off >>= 1) rp += __shfl_xor(rp, off);
            if (lane == 0) rsum[tt][m] = rp;
        }
    }
    __syncthreads();

    // Phase 2: P[32 x 1024] @ Wh[1024 x 256] with 1-step register prefetch.
    const unsigned short* WB = WhF + (size_t)b * (N_ * H_);
    int rs = (lane ^ ((lane >> 3) & 7)) * 8;   // swizzled read offset (shorts)
    floatx4 acc0[4], acc1[4];
#pragma unroll
    for (int cc = 0; cc < 4; ++cc) {
        acc0[cc] = (floatx4){0.f, 0.f, 0.f, 0.f};
        acc1[cc] = (floatx4){0.f, 0.f, 0.f, 0.f};
    }
    bf16x8 af0 = *reinterpret_cast<const bf16x8*>(pfrag[0] + rs);
    bf16x8 af1 = *reinterpret_cast<const bf16x8*>(pfrag[1] + rs);
    bf16x8 bfv[4];
#pragma unroll
    for (int cc = 0; cc < 4; ++cc)
        bfv[cc] = *reinterpret_cast<const bf16x8*>(
            WB + ((size_t)((w * 4 + cc) * 64 + lane)) * 8);
    for (int ks = 0; ks < 32; ++ks) {
        bf16x8 naf0, naf1, nbf[4];
        if (ks < 31) {
            naf0 = *reinterpret_cast<const bf16x8*>(pfrag[0] + (ks + 1) * PF_PITCH + rs);
            naf1 = *reinterpret_cast<const bf16x8*>(pfrag[1] + (ks + 1) * PF_PITCH + rs);
#pragma unroll
            for (int cc = 0; cc < 4; ++cc)
                nbf[cc] = *reinterpret_cast<const bf16x8*>(
                    WB + ((size_t)(((ks + 1) * 16 + w * 4 + cc) * 64 + lane)) * 8);
        }
#pragma unroll
        for (int cc = 0; cc < 4; ++cc) {
            acc0[cc] = __builtin_amdgcn_mfma_f32_16x16x32_bf16(af0, bfv[cc], acc0[cc], 0, 0, 0);
            acc1[cc] = __builtin_amdgcn_mfma_f32_16x16x32_bf16(af1, bfv[cc], acc1[cc], 0, 0, 0);
        }
        if (ks < 31) {
            af0 = naf0; af1 = naf1;
#pragma unroll
            for (int cc = 0; cc < 4; ++cc) bfv[cc] = nbf[cc];
        }
    }

    // Epilogue: normalize (fp32 sums from LDS), elu, store.
    int quad = lane >> 4, m16 = lane & 15;
    float inv0[4], inv1[4];
#pragma unroll
    for (int r = 0; r < 4; ++r) {
        inv0[r] = 1.0f / rsum[0][quad * 4 + r];
        inv1[r] = 1.0f / rsum[1][quad * 4 + r];
    }
#pragma unroll
    for (int cc = 0; cc < 4; ++cc) {
        int col = (w * 4 + cc) * 16 + m16;
#pragma unroll
        for (int r = 0; r < 4; ++r) {
            int m = quad * 4 + r;
            float v0 = acc0[cc][r] * inv0[r];
            v0 = v0 > 0.f ? v0 : __expf(v0) - 1.0f;
            out[((size_t)(b * N_ + rowbase + m)) * H_ + col] = v0;
            float v1 = acc1[cc][r] * inv1[r];
            v1 = v1 > 0.f ? v1 : __expf(v1) - 1.0f;
            out[((size_t)(b * N_ + rowbase + 16 + m)) * H_ + col] = v1;
        }
    }
}

// ---------------------------------------------------------------------------
extern "C" void kernel_launch(void* const* d_in, const int* in_sizes, int n_in,
                              void* d_out, int out_size, void* d_ws, size_t ws_size,
                              hipStream_t stream) {
    const float* inp = (const float*)d_in[0];
    const float* A   = (const float*)d_in[1];
    const int*   l   = (const int*)d_in[2];
    const float* Wi  = (const float*)d_in[3];
    const float* Wc  = (const float*)d_in[4];
    const float* a   = (const float*)d_in[5];
    float* out = (float*)d_out;

    char* ws = (char*)d_ws;
    size_t off = 0;
    unsigned short* WhF  = (unsigned short*)(ws + off); off += (size_t)B_ * N_ * H_ * 2;
    float* Wh1 = (float*)(ws + off); off += (size_t)B_ * N_ * 4;
    float* Wh2 = (float*)(ws + off); off += (size_t)B_ * N_ * 4;
    float* U   = (float*)(ws + off); off += 4 * H_ * 4;
    unsigned short* WtFi = (unsigned short*)(ws + off); off += (size_t)H_ * H_ * 2;
    unsigned short* WtFc = (unsigned short*)(ws + off); off += (size_t)H_ * H_ * 2;
    unsigned int* Mask = (unsigned int*)(ws + off); off += (size_t)B_ * N_ * 32 * 4;

    k_pre<<<32 + H_, 256, 0, stream>>>(Wi, Wc, a, U, WtFi, WtFc);
    k_abits<<<(B_ * N_) / 8, 256, 0, stream>>>(A, Mask);
    k_gemm<<<B_ * 16 * 2, 256, 0, stream>>>(inp, l, WtFi, WtFc, WhF, U, Wh1, Wh2);
    k_attn<<<B_ * (N_ / 32), 256, 0, stream>>>(Mask, Wh1, Wh2, WhF, out);
}